// Round 1
// baseline (26315.891 us; speedup 1.0000x reference)
//
#include <hip/hip_runtime.h>

#define NSVC 2000
#define NPOD 8000
#define NNODE 1000
#define NTOT 11000
#define TT 32
#define FF 64
#define HH 128
#define EA 30000
#define EB 24000
#define EC 24000

// ---------------- degree counting ----------------
__global__ void k_count(const int* __restrict__ src, const int* __restrict__ dst, int E,
                        float* oc, float* ic) {
    int e = blockIdx.x * 256 + threadIdx.x;
    if (e < E) {
        atomicAdd(oc + src[e], 1.f);
        atomicAdd(ic + dst[e], 1.f);
    }
}

// ---------------- prefix scan (3 graphs, one block each) ----------------
__global__ void k_scan(const float* cA, int nA, int* oA,
                       const float* cB, int nB, int* oB,
                       const float* cC, int nC, int* oC) {
    const float* c; int n; int* o;
    if (blockIdx.x == 0)      { c = cA; n = nA; o = oA; }
    else if (blockIdx.x == 1) { c = cB; n = nB; o = oB; }
    else                      { c = cC; n = nC; o = oC; }
    __shared__ int s[256];
    __shared__ int carry;
    int tid = threadIdx.x;
    if (tid == 0) { carry = 0; o[0] = 0; }
    __syncthreads();
    for (int base = 0; base < n; base += 256) {
        int idx = base + tid;
        int v = (idx < n) ? (int)c[idx] : 0;
        s[tid] = v;
        __syncthreads();
        for (int d = 1; d < 256; d <<= 1) {
            int t = (tid >= d) ? s[tid - d] : 0;
            __syncthreads();
            s[tid] += t;
            __syncthreads();
        }
        if (idx < n) o[idx + 1] = carry + s[tid];
        __syncthreads();
        if (tid == 255) carry += s[255];
        __syncthreads();
    }
}

// ---------------- CSR scatter ----------------
__global__ void k_scatter(const int* __restrict__ src, const int* __restrict__ dst, int E,
                          const int* __restrict__ off, int* cur, int* csr) {
    int e = blockIdx.x * 256 + threadIdx.x;
    if (e < E) {
        int d = dst[e];
        int p = atomicAdd(cur + d, 1);
        csr[off[d] + p] = src[e];
    }
}

// ---------------- fused conv: aggregate + W + b + leaky + lw dot + lb ----------------
__global__ __launch_bounds__(256) void k_conv(
    const float* __restrict__ x,    // [Nsrc, 32, 64]
    const float* __restrict__ w,    // [32, 64, 128]
    const float* __restrict__ b,    // [32, 128]
    const float* __restrict__ lw,   // [32, 128]
    const float* __restrict__ lb,   // [32]
    const float* __restrict__ oc,   // out-deg counts [Nsrc]
    const float* __restrict__ ic,   // in-deg counts [Ndst]
    const int* __restrict__ off, const int* __restrict__ csr,
    float* __restrict__ xseq, int Ndst, int rowofs)
{
    __shared__ float wl[FF * HH];
    __shared__ float bl[HH], lwl[HH];
    __shared__ float accs[4][FF];
    int t = blockIdx.x;
    int tid = threadIdx.x;
    for (int i = tid; i < FF * HH; i += 256) wl[i] = w[t * FF * HH + i];
    if (tid < HH) { bl[tid] = b[t * HH + tid]; lwl[tid] = lw[t * HH + tid]; }
    int wv = tid >> 6, lane = tid & 63;
    int dstn = blockIdx.y * 4 + wv;
    __syncthreads();
    if (dstn < Ndst) {
        float a = 0.f;
        int e0 = off[dstn], e1 = off[dstn + 1];
        for (int i = e0; i < e1; ++i) {
            int s = csr[i];
            float xs = x[(size_t)s * (TT * FF) + t * FF + lane];
            a += xs * rsqrtf(fmaxf(oc[s], 1.f));
        }
        a *= rsqrtf(fmaxf(ic[dstn], 1.f));
        accs[wv][lane] = a;
    }
    __syncthreads();
    if (dstn < Ndst) {
        float h0 = bl[lane], h1v = bl[64 + lane];
        #pragma unroll
        for (int f = 0; f < FF; ++f) {
            float af = accs[wv][f];
            h0  += af * wl[f * HH + lane];
            h1v += af * wl[f * HH + 64 + lane];
        }
        h0  = (h0  >= 0.f) ? h0  : 0.01f * h0;
        h1v = (h1v >= 0.f) ? h1v : 0.01f * h1v;
        float p = h0 * lwl[lane] + h1v * lwl[64 + lane];
        #pragma unroll
        for (int o2 = 32; o2 >= 1; o2 >>= 1) p += __shfl_down(p, o2);
        if (lane == 0) xseq[(size_t)(rowofs + dstn) * TT + t] = p + lb[t];
    }
}

// ---------------- input projection: X = xin @ wih^T + (bih + bhh) ----------------
__global__ __launch_bounds__(256) void k_proj(
    const float* __restrict__ xin, int K,      // [N, K]
    const float* __restrict__ wih,             // [512, K]
    const float* __restrict__ bih, const float* __restrict__ bhh,
    float* __restrict__ Xout, int N)           // [N, 512]
{
    __shared__ float xt[16 * 128];
    int n0 = blockIdx.x * 16, tid = threadIdx.x;
    for (int i = tid; i < 16 * K; i += 256) {
        int nn = i / K, kk = i - nn * K;
        int n = n0 + nn;
        xt[i] = (n < N) ? xin[(size_t)n * K + kk] : 0.f;
    }
    __syncthreads();
    float acc0[16], acc1[16];
    #pragma unroll
    for (int i = 0; i < 16; ++i) { acc0[i] = 0.f; acc1[i] = 0.f; }
    int r0 = tid, r1 = tid + 256;
    for (int k = 0; k < K; ++k) {
        float w0 = wih[(size_t)r0 * K + k];
        float w1 = wih[(size_t)r1 * K + k];
        #pragma unroll
        for (int i = 0; i < 16; ++i) {
            float xv = xt[i * K + k];
            acc0[i] += xv * w0;
            acc1[i] += xv * w1;
        }
    }
    float b0 = bih[r0] + bhh[r0], b1 = bih[r1] + bhh[r1];
    for (int i = 0; i < 16; ++i) {
        int n = n0 + i;
        if (n < N) {
            Xout[(size_t)n * 512 + r0] = acc0[i] + b0;
            Xout[(size_t)n * 512 + r1] = acc1[i] + b1;
        }
    }
}

// ---------------- sequential LSTM layer (1 block = 1 CU) ----------------
__global__ __launch_bounds__(512, 2) void k_lstm(
    const float* __restrict__ X,    // [N, 512]  precomputed x@Wih^T + b
    const float* __restrict__ Whh,  // [512, 128]
    float* __restrict__ Hout,       // [N, 128]
    int N)
{
    __shared__ __align__(16) float hlds[HH];
    __shared__ float act[512];
    const int r = threadIdx.x;
    // preload Whh row into registers
    float w[HH];
    #pragma unroll
    for (int k4 = 0; k4 < HH / 4; ++k4) {
        float4 v = reinterpret_cast<const float4*>(Whh + (size_t)r * HH)[k4];
        w[4 * k4 + 0] = v.x; w[4 * k4 + 1] = v.y;
        w[4 * k4 + 2] = v.z; w[4 * k4 + 3] = v.w;
    }
    if (r < HH) hlds[r] = 0.f;
    float c = 0.f;
    float xcur = X[r];
    __syncthreads();
    for (int n = 0; n < N; ++n) {
        float acc = xcur;
        float xnext = (n + 1 < N) ? X[(size_t)(n + 1) * 512 + r] : 0.f;
        #pragma unroll
        for (int k4 = 0; k4 < HH / 4; ++k4) {
            float4 h4 = reinterpret_cast<const float4*>(hlds)[k4];
            acc += w[4 * k4 + 0] * h4.x + w[4 * k4 + 1] * h4.y
                 + w[4 * k4 + 2] * h4.z + w[4 * k4 + 3] * h4.w;
        }
        float a;
        if (r >= 256 && r < 384) {
            a = 1.f - 2.f / (1.f + __expf(2.f * acc));     // tanh, overflow-safe
        } else {
            a = 1.f / (1.f + __expf(-acc));                // sigmoid
        }
        act[r] = a;
        __syncthreads();
        if (r < HH) {
            float gi = act[r], gf = act[HH + r], gg = act[2 * HH + r], go = act[3 * HH + r];
            c = gf * c + gi * gg;
            float h = go * (1.f - 2.f / (1.f + __expf(2.f * c)));
            hlds[r] = h;
            Hout[(size_t)n * HH + r] = h;
        }
        xcur = xnext;
        __syncthreads();
    }
}

extern "C" void kernel_launch(void* const* d_in, const int* in_sizes, int n_in,
                              void* d_out, int out_size, void* d_ws, size_t ws_size,
                              hipStream_t stream) {
    const float* feat_svc = (const float*)d_in[0];
    const float* feat_pod = (const float*)d_in[1];
    const float* feat_node= (const float*)d_in[2];
    const float* w_svc = (const float*)d_in[3];
    const float* b_svc = (const float*)d_in[4];
    const float* w_in  = (const float*)d_in[5];
    const float* b_in  = (const float*)d_in[6];
    const float* w_ni  = (const float*)d_in[7];
    const float* b_ni  = (const float*)d_in[8];
    const float* lw_svc = (const float*)d_in[9];
    const float* lb_svc = (const float*)d_in[10];
    const float* lw_pod = (const float*)d_in[11];
    const float* lb_pod = (const float*)d_in[12];
    const float* lw_node= (const float*)d_in[13];
    const float* lb_node= (const float*)d_in[14];
    const float* w_ih0 = (const float*)d_in[15];
    const float* w_hh0 = (const float*)d_in[16];
    const float* b_ih0 = (const float*)d_in[17];
    const float* b_hh0 = (const float*)d_in[18];
    const float* w_ih1 = (const float*)d_in[19];
    const float* w_hh1 = (const float*)d_in[20];
    const float* b_ih1 = (const float*)d_in[21];
    const float* b_hh1 = (const float*)d_in[22];
    const int* eA_src = (const int*)d_in[23];   // svc -> svc
    const int* eA_dst = (const int*)d_in[24];
    const int* eB_src = (const int*)d_in[25];   // pod -> node
    const int* eB_dst = (const int*)d_in[26];
    const int* eC_src = (const int*)d_in[27];   // node -> pod
    const int* eC_dst = (const int*)d_in[28];

    float* ws = (float*)d_ws;
    // layout (4B units)
    float* ocA = ws + 0;        // 2000
    float* icA = ws + 2000;     // 2000
    float* ocB = ws + 4000;     // 8000 (pod out-deg)
    float* icB = ws + 12000;    // 1000 (node in-deg)
    float* ocC = ws + 13000;    // 1000 (node out-deg)
    float* icC = ws + 14000;    // 8000 (pod in-deg)
    int* curA = (int*)(ws + 22000);  // 2000
    int* curB = (int*)(ws + 24000);  // 1000
    int* curC = (int*)(ws + 25000);  // 8000
    int* offA = (int*)(ws + 33000);  // 2001
    int* offB = (int*)(ws + 35001);  // 1001
    int* offC = (int*)(ws + 36002);  // 8001
    int* sA   = (int*)(ws + 44003);  // 30000
    int* sB   = (int*)(ws + 74003);  // 24000
    int* sC   = (int*)(ws + 98003);  // 24000
    float* xseq = ws + 122003;       // 11000*32
    float* X1   = ws + 474003;       // 11000*512
    float* h1   = ws + 6106003;      // 11000*128
    float* X2   = X1;                // reuse: X1 dead after k_lstm layer 1

    // zero deg counts + cursors
    hipMemsetAsync(d_ws, 0, 33000 * sizeof(float), stream);

    k_count<<<(EA + 255) / 256, 256, 0, stream>>>(eA_src, eA_dst, EA, ocA, icA);
    k_count<<<(EB + 255) / 256, 256, 0, stream>>>(eB_src, eB_dst, EB, ocB, icB);
    k_count<<<(EC + 255) / 256, 256, 0, stream>>>(eC_src, eC_dst, EC, ocC, icC);

    k_scan<<<3, 256, 0, stream>>>(icA, NSVC, offA, icB, NNODE, offB, icC, NPOD, offC);

    k_scatter<<<(EA + 255) / 256, 256, 0, stream>>>(eA_src, eA_dst, EA, offA, curA, sA);
    k_scatter<<<(EB + 255) / 256, 256, 0, stream>>>(eB_src, eB_dst, EB, offB, curB, sB);
    k_scatter<<<(EC + 255) / 256, 256, 0, stream>>>(eC_src, eC_dst, EC, offC, curC, sC);

    // conv A: svc->svc, scores with lw_svc, rows [0, 2000)
    k_conv<<<dim3(TT, (NSVC + 3) / 4), 256, 0, stream>>>(
        feat_svc, w_svc, b_svc, lw_svc, lb_svc, ocA, icA, offA, sA, xseq, NSVC, 0);
    // conv C: node->pod (h_pod uses w_ni), scores with lw_pod, rows [2000, 10000)
    k_conv<<<dim3(TT, (NPOD + 3) / 4), 256, 0, stream>>>(
        feat_node, w_ni, b_ni, lw_pod, lb_pod, ocC, icC, offC, sC, xseq, NPOD, NSVC);
    // conv B: pod->node (h_node uses w_in), scores with lw_node, rows [10000, 11000)
    k_conv<<<dim3(TT, (NNODE + 3) / 4), 256, 0, stream>>>(
        feat_pod, w_in, b_in, lw_node, lb_node, ocB, icB, offB, sB, xseq, NNODE, NSVC + NPOD);

    // LSTM layer 1
    k_proj<<<(NTOT + 15) / 16, 256, 0, stream>>>(xseq, TT, w_ih0, b_ih0, b_hh0, X1, NTOT);
    k_lstm<<<1, 512, 0, stream>>>(X1, w_hh0, h1, NTOT);
    // LSTM layer 2
    k_proj<<<(NTOT + 15) / 16, 256, 0, stream>>>(h1, HH, w_ih1, b_ih1, b_hh1, X2, NTOT);
    k_lstm<<<1, 512, 0, stream>>>(X2, w_hh1, (float*)d_out, NTOT);
}

// Round 2
// 21275.677 us; speedup vs baseline: 1.2369x; 1.2369x over previous
//
#include <hip/hip_runtime.h>

#define NSVC 2000
#define NPOD 8000
#define NNODE 1000
#define NTOT 11000
#define TT 32
#define FF 64
#define HH 128
#define EA 30000
#define EB 24000
#define EC 24000

// ---------------- degree counting ----------------
__global__ void k_count(const int* __restrict__ src, const int* __restrict__ dst, int E,
                        float* oc, float* ic) {
    int e = blockIdx.x * 256 + threadIdx.x;
    if (e < E) {
        atomicAdd(oc + src[e], 1.f);
        atomicAdd(ic + dst[e], 1.f);
    }
}

// ---------------- prefix scan (3 graphs, one block each) ----------------
__global__ void k_scan(const float* cA, int nA, int* oA,
                       const float* cB, int nB, int* oB,
                       const float* cC, int nC, int* oC) {
    const float* c; int n; int* o;
    if (blockIdx.x == 0)      { c = cA; n = nA; o = oA; }
    else if (blockIdx.x == 1) { c = cB; n = nB; o = oB; }
    else                      { c = cC; n = nC; o = oC; }
    __shared__ int s[256];
    __shared__ int carry;
    int tid = threadIdx.x;
    if (tid == 0) { carry = 0; o[0] = 0; }
    __syncthreads();
    for (int base = 0; base < n; base += 256) {
        int idx = base + tid;
        int v = (idx < n) ? (int)c[idx] : 0;
        s[tid] = v;
        __syncthreads();
        for (int d = 1; d < 256; d <<= 1) {
            int t = (tid >= d) ? s[tid - d] : 0;
            __syncthreads();
            s[tid] += t;
            __syncthreads();
        }
        if (idx < n) o[idx + 1] = carry + s[tid];
        __syncthreads();
        if (tid == 255) carry += s[255];
        __syncthreads();
    }
}

// ---------------- CSR scatter ----------------
__global__ void k_scatter(const int* __restrict__ src, const int* __restrict__ dst, int E,
                          const int* __restrict__ off, int* cur, int* csr) {
    int e = blockIdx.x * 256 + threadIdx.x;
    if (e < E) {
        int d = dst[e];
        int p = atomicAdd(cur + d, 1);
        csr[off[d] + p] = src[e];
    }
}

// ---------------- fused conv: aggregate + W + b + leaky + lw dot + lb ----------------
__global__ __launch_bounds__(256) void k_conv(
    const float* __restrict__ x,    // [Nsrc, 32, 64]
    const float* __restrict__ w,    // [32, 64, 128]
    const float* __restrict__ b,    // [32, 128]
    const float* __restrict__ lw,   // [32, 128]
    const float* __restrict__ lb,   // [32]
    const float* __restrict__ oc,   // out-deg counts [Nsrc]
    const float* __restrict__ ic,   // in-deg counts [Ndst]
    const int* __restrict__ off, const int* __restrict__ csr,
    float* __restrict__ xseq, int Ndst, int rowofs)
{
    __shared__ float wl[FF * HH];
    __shared__ float bl[HH], lwl[HH];
    __shared__ float accs[4][FF];
    int t = blockIdx.x;
    int tid = threadIdx.x;
    for (int i = tid; i < FF * HH; i += 256) wl[i] = w[t * FF * HH + i];
    if (tid < HH) { bl[tid] = b[t * HH + tid]; lwl[tid] = lw[t * HH + tid]; }
    int wv = tid >> 6, lane = tid & 63;
    int dstn = blockIdx.y * 4 + wv;
    __syncthreads();
    if (dstn < Ndst) {
        float a = 0.f;
        int e0 = off[dstn], e1 = off[dstn + 1];
        for (int i = e0; i < e1; ++i) {
            int s = csr[i];
            float xs = x[(size_t)s * (TT * FF) + t * FF + lane];
            a += xs * rsqrtf(fmaxf(oc[s], 1.f));
        }
        a *= rsqrtf(fmaxf(ic[dstn], 1.f));
        accs[wv][lane] = a;
    }
    __syncthreads();
    if (dstn < Ndst) {
        float h0 = bl[lane], h1v = bl[64 + lane];
        #pragma unroll
        for (int f = 0; f < FF; ++f) {
            float af = accs[wv][f];
            h0  += af * wl[f * HH + lane];
            h1v += af * wl[f * HH + 64 + lane];
        }
        h0  = (h0  >= 0.f) ? h0  : 0.01f * h0;
        h1v = (h1v >= 0.f) ? h1v : 0.01f * h1v;
        float p = h0 * lwl[lane] + h1v * lwl[64 + lane];
        #pragma unroll
        for (int o2 = 32; o2 >= 1; o2 >>= 1) p += __shfl_down(p, o2);
        if (lane == 0) xseq[(size_t)(rowofs + dstn) * TT + t] = p + lb[t];
    }
}

// ---------------- input projection: X = xin @ wih^T + (bih + bhh) ----------------
__global__ __launch_bounds__(256) void k_proj(
    const float* __restrict__ xin, int K,      // [N, K]
    const float* __restrict__ wih,             // [512, K]
    const float* __restrict__ bih, const float* __restrict__ bhh,
    float* __restrict__ Xout, int N)           // [N, 512]
{
    __shared__ float xt[16 * 128];
    int n0 = blockIdx.x * 16, tid = threadIdx.x;
    for (int i = tid; i < 16 * K; i += 256) {
        int nn = i / K, kk = i - nn * K;
        int n = n0 + nn;
        xt[i] = (n < N) ? xin[(size_t)n * K + kk] : 0.f;
    }
    __syncthreads();
    float acc0[16], acc1[16];
    #pragma unroll
    for (int i = 0; i < 16; ++i) { acc0[i] = 0.f; acc1[i] = 0.f; }
    int r0 = tid, r1 = tid + 256;
    for (int k = 0; k < K; ++k) {
        float w0 = wih[(size_t)r0 * K + k];
        float w1 = wih[(size_t)r1 * K + k];
        #pragma unroll
        for (int i = 0; i < 16; ++i) {
            float xv = xt[i * K + k];
            acc0[i] += xv * w0;
            acc1[i] += xv * w1;
        }
    }
    float b0 = bih[r0] + bhh[r0], b1 = bih[r1] + bhh[r1];
    for (int i = 0; i < 16; ++i) {
        int n = n0 + i;
        if (n < N) {
            Xout[(size_t)n * 512 + r0] = acc0[i] + b0;
            Xout[(size_t)n * 512 + r1] = acc1[i] + b1;
        }
    }
}

// ---------------- sequential LSTM layer (1 block = 1 CU) ----------------
// thread = (j, p): hidden unit j = tid>>2, k-chunk p = tid&3.
// Each thread: 4 gate-rows x 32 k-slice of Whh in VGPRs; reads 32 h from LDS;
// 4 independent 32-FMA chains; butterfly reduce over 4 p-lanes via shfl_xor;
// cell computed redundantly in the 4 lanes; double-buffered h, ONE barrier/step.
__global__ __launch_bounds__(512, 2) void k_lstm(
    const float* __restrict__ X,    // [N, 512]  precomputed x@Wih^T + b (gate-major i,f,g,o)
    const float* __restrict__ Whh,  // [512, 128]
    float* __restrict__ Hout,       // [N, 128]
    int N)
{
    __shared__ __align__(16) float hbuf[2][HH];
    const int tid = threadIdx.x;
    const int j = tid >> 2;        // hidden unit
    const int p = tid & 3;         // k-chunk / gate assignment
    // w[g][k] = Whh[(g*128 + j)*128 + p*32 + k]
    float w[4][32];
    #pragma unroll
    for (int g = 0; g < 4; ++g) {
        const float* wr = Whh + (size_t)(g * HH + j) * HH + p * 32;
        #pragma unroll
        for (int k4 = 0; k4 < 8; ++k4) {
            float4 v = reinterpret_cast<const float4*>(wr)[k4];
            w[g][4 * k4 + 0] = v.x; w[g][4 * k4 + 1] = v.y;
            w[g][4 * k4 + 2] = v.z; w[g][4 * k4 + 3] = v.w;
        }
    }
    if (tid < HH) hbuf[0][tid] = 0.f;
    float c = 0.f;
    float xcur = X[p * HH + j];
    int cur = 0;
    __syncthreads();
    for (int n = 0; n < N; ++n) {
        float h[32];
        #pragma unroll
        for (int k4 = 0; k4 < 8; ++k4) {
            float4 v = reinterpret_cast<const float4*>(&hbuf[cur][p * 32])[k4];
            h[4 * k4 + 0] = v.x; h[4 * k4 + 1] = v.y;
            h[4 * k4 + 2] = v.z; h[4 * k4 + 3] = v.w;
        }
        float xnext = (n + 1 < N) ? X[(size_t)(n + 1) * 512 + p * HH + j] : 0.f;
        float s0 = 0.f, s1 = 0.f, s2 = 0.f, s3 = 0.f;
        #pragma unroll
        for (int k = 0; k < 32; ++k) {
            float hv = h[k];
            s0 += w[0][k] * hv;
            s1 += w[1][k] * hv;
            s2 += w[2][k] * hv;
            s3 += w[3][k] * hv;
        }
        // fold in the X term: lane p owns gate p's X value
        if      (p == 0) s0 += xcur;
        else if (p == 1) s1 += xcur;
        else if (p == 2) s2 += xcur;
        else             s3 += xcur;
        // butterfly reduce over the 4 p-lanes; all 4 end with full totals
        s0 += __shfl_xor(s0, 1); s1 += __shfl_xor(s1, 1);
        s2 += __shfl_xor(s2, 1); s3 += __shfl_xor(s3, 1);
        s0 += __shfl_xor(s0, 2); s1 += __shfl_xor(s1, 2);
        s2 += __shfl_xor(s2, 2); s3 += __shfl_xor(s3, 2);
        // LSTM cell (redundant in 4 lanes; identical results)
        float gi = 1.f / (1.f + __expf(-s0));
        float gf = 1.f / (1.f + __expf(-s1));
        float gg = 1.f - 2.f / (1.f + __expf(2.f * s2));   // tanh
        float go = 1.f / (1.f + __expf(-s3));
        c = gf * c + gi * gg;
        float hnew = go * (1.f - 2.f / (1.f + __expf(2.f * c)));
        if (p == 0) {
            hbuf[cur ^ 1][j] = hnew;
            Hout[(size_t)n * HH + j] = hnew;
        }
        xcur = xnext;
        cur ^= 1;
        __syncthreads();
    }
}

extern "C" void kernel_launch(void* const* d_in, const int* in_sizes, int n_in,
                              void* d_out, int out_size, void* d_ws, size_t ws_size,
                              hipStream_t stream) {
    const float* feat_svc = (const float*)d_in[0];
    const float* feat_pod = (const float*)d_in[1];
    const float* feat_node= (const float*)d_in[2];
    const float* w_svc = (const float*)d_in[3];
    const float* b_svc = (const float*)d_in[4];
    const float* w_in  = (const float*)d_in[5];
    const float* b_in  = (const float*)d_in[6];
    const float* w_ni  = (const float*)d_in[7];
    const float* b_ni  = (const float*)d_in[8];
    const float* lw_svc = (const float*)d_in[9];
    const float* lb_svc = (const float*)d_in[10];
    const float* lw_pod = (const float*)d_in[11];
    const float* lb_pod = (const float*)d_in[12];
    const float* lw_node= (const float*)d_in[13];
    const float* lb_node= (const float*)d_in[14];
    const float* w_ih0 = (const float*)d_in[15];
    const float* w_hh0 = (const float*)d_in[16];
    const float* b_ih0 = (const float*)d_in[17];
    const float* b_hh0 = (const float*)d_in[18];
    const float* w_ih1 = (const float*)d_in[19];
    const float* w_hh1 = (const float*)d_in[20];
    const float* b_ih1 = (const float*)d_in[21];
    const float* b_hh1 = (const float*)d_in[22];
    const int* eA_src = (const int*)d_in[23];   // svc -> svc
    const int* eA_dst = (const int*)d_in[24];
    const int* eB_src = (const int*)d_in[25];   // pod -> node
    const int* eB_dst = (const int*)d_in[26];
    const int* eC_src = (const int*)d_in[27];   // node -> pod
    const int* eC_dst = (const int*)d_in[28];

    float* ws = (float*)d_ws;
    // layout (4B units)
    float* ocA = ws + 0;        // 2000
    float* icA = ws + 2000;     // 2000
    float* ocB = ws + 4000;     // 8000 (pod out-deg)
    float* icB = ws + 12000;    // 1000 (node in-deg)
    float* ocC = ws + 13000;    // 1000 (node out-deg)
    float* icC = ws + 14000;    // 8000 (pod in-deg)
    int* curA = (int*)(ws + 22000);  // 2000
    int* curB = (int*)(ws + 24000);  // 1000
    int* curC = (int*)(ws + 25000);  // 8000
    int* offA = (int*)(ws + 33000);  // 2001
    int* offB = (int*)(ws + 35001);  // 1001
    int* offC = (int*)(ws + 36002);  // 8001
    int* sA   = (int*)(ws + 44003);  // 30000
    int* sB   = (int*)(ws + 74003);  // 24000
    int* sC   = (int*)(ws + 98003);  // 24000
    float* xseq = ws + 122003;       // 11000*32
    float* X1   = ws + 474003;       // 11000*512
    float* h1   = ws + 6106003;      // 11000*128
    float* X2   = X1;                // reuse: X1 dead after k_lstm layer 1

    // zero deg counts + cursors
    hipMemsetAsync(d_ws, 0, 33000 * sizeof(float), stream);

    k_count<<<(EA + 255) / 256, 256, 0, stream>>>(eA_src, eA_dst, EA, ocA, icA);
    k_count<<<(EB + 255) / 256, 256, 0, stream>>>(eB_src, eB_dst, EB, ocB, icB);
    k_count<<<(EC + 255) / 256, 256, 0, stream>>>(eC_src, eC_dst, EC, ocC, icC);

    k_scan<<<3, 256, 0, stream>>>(icA, NSVC, offA, icB, NNODE, offB, icC, NPOD, offC);

    k_scatter<<<(EA + 255) / 256, 256, 0, stream>>>(eA_src, eA_dst, EA, offA, curA, sA);
    k_scatter<<<(EB + 255) / 256, 256, 0, stream>>>(eB_src, eB_dst, EB, offB, curB, sB);
    k_scatter<<<(EC + 255) / 256, 256, 0, stream>>>(eC_src, eC_dst, EC, offC, curC, sC);

    // conv A: svc->svc, scores with lw_svc, rows [0, 2000)
    k_conv<<<dim3(TT, (NSVC + 3) / 4), 256, 0, stream>>>(
        feat_svc, w_svc, b_svc, lw_svc, lb_svc, ocA, icA, offA, sA, xseq, NSVC, 0);
    // conv C: node->pod (h_pod uses w_ni), scores with lw_pod, rows [2000, 10000)
    k_conv<<<dim3(TT, (NPOD + 3) / 4), 256, 0, stream>>>(
        feat_node, w_ni, b_ni, lw_pod, lb_pod, ocC, icC, offC, sC, xseq, NPOD, NSVC);
    // conv B: pod->node (h_node uses w_in), scores with lw_node, rows [10000, 11000)
    k_conv<<<dim3(TT, (NNODE + 3) / 4), 256, 0, stream>>>(
        feat_pod, w_in, b_in, lw_node, lb_node, ocB, icB, offB, sB, xseq, NNODE, NSVC + NPOD);

    // LSTM layer 1
    k_proj<<<(NTOT + 15) / 16, 256, 0, stream>>>(xseq, TT, w_ih0, b_ih0, b_hh0, X1, NTOT);
    k_lstm<<<1, 512, 0, stream>>>(X1, w_hh0, h1, NTOT);
    // LSTM layer 2
    k_proj<<<(NTOT + 15) / 16, 256, 0, stream>>>(h1, HH, w_ih1, b_ih1, b_hh1, X2, NTOT);
    k_lstm<<<1, 512, 0, stream>>>(X2, w_hh1, (float*)d_out, NTOT);
}

// Round 3
// 10302.491 us; speedup vs baseline: 2.5543x; 2.0651x over previous
//
#include <hip/hip_runtime.h>

#define NSVC 2000
#define NPOD 8000
#define NNODE 1000
#define NTOT 11000
#define TT 32
#define FF 64
#define HH 128
#define EA 30000
#define EB 24000
#define EC 24000
#define CHK 64
#define NCH ((NTOT + CHK - 1) / CHK)   // 172

// ---------------- agent-scope helpers (cross-XCD safe) ----------------
__device__ __forceinline__ float ld_agent(const float* p) {
    return __hip_atomic_load(p, __ATOMIC_RELAXED, __HIP_MEMORY_SCOPE_AGENT);
}
__device__ __forceinline__ void st_agent(float* p, float v) {
    __hip_atomic_store(p, v, __ATOMIC_RELAXED, __HIP_MEMORY_SCOPE_AGENT);
}
// barrier that does NOT drain vmcnt (keeps global loads/stores in flight)
__device__ __forceinline__ void bar_fast() {
    asm volatile("s_waitcnt lgkmcnt(0)" ::: "memory");
    __builtin_amdgcn_s_barrier();
}

// ---------------- degree counting ----------------
__global__ void k_count(const int* __restrict__ src, const int* __restrict__ dst, int E,
                        float* oc, float* ic) {
    int e = blockIdx.x * 256 + threadIdx.x;
    if (e < E) {
        atomicAdd(oc + src[e], 1.f);
        atomicAdd(ic + dst[e], 1.f);
    }
}

// ---------------- prefix scan (3 graphs, one block each) ----------------
__global__ void k_scan(const float* cA, int nA, int* oA,
                       const float* cB, int nB, int* oB,
                       const float* cC, int nC, int* oC) {
    const float* c; int n; int* o;
    if (blockIdx.x == 0)      { c = cA; n = nA; o = oA; }
    else if (blockIdx.x == 1) { c = cB; n = nB; o = oB; }
    else                      { c = cC; n = nC; o = oC; }
    __shared__ int s[256];
    __shared__ int carry;
    int tid = threadIdx.x;
    if (tid == 0) { carry = 0; o[0] = 0; }
    __syncthreads();
    for (int base = 0; base < n; base += 256) {
        int idx = base + tid;
        int v = (idx < n) ? (int)c[idx] : 0;
        s[tid] = v;
        __syncthreads();
        for (int d = 1; d < 256; d <<= 1) {
            int t = (tid >= d) ? s[tid - d] : 0;
            __syncthreads();
            s[tid] += t;
            __syncthreads();
        }
        if (idx < n) o[idx + 1] = carry + s[tid];
        __syncthreads();
        if (tid == 255) carry += s[255];
        __syncthreads();
    }
}

// ---------------- CSR scatter ----------------
__global__ void k_scatter(const int* __restrict__ src, const int* __restrict__ dst, int E,
                          const int* __restrict__ off, int* cur, int* csr) {
    int e = blockIdx.x * 256 + threadIdx.x;
    if (e < E) {
        int d = dst[e];
        int p = atomicAdd(cur + d, 1);
        csr[off[d] + p] = src[e];
    }
}

// ---------------- fused conv: aggregate + W + b + leaky + lw dot + lb ----------------
__global__ __launch_bounds__(256) void k_conv(
    const float* __restrict__ x,    // [Nsrc, 32, 64]
    const float* __restrict__ w,    // [32, 64, 128]
    const float* __restrict__ b,    // [32, 128]
    const float* __restrict__ lw,   // [32, 128]
    const float* __restrict__ lb,   // [32]
    const float* __restrict__ oc,   // out-deg counts [Nsrc]
    const float* __restrict__ ic,   // in-deg counts [Ndst]
    const int* __restrict__ off, const int* __restrict__ csr,
    float* __restrict__ xseq, int Ndst, int rowofs)
{
    __shared__ float wl[FF * HH];
    __shared__ float bl[HH], lwl[HH];
    __shared__ float accs[4][FF];
    int t = blockIdx.x;
    int tid = threadIdx.x;
    for (int i = tid; i < FF * HH; i += 256) wl[i] = w[t * FF * HH + i];
    if (tid < HH) { bl[tid] = b[t * HH + tid]; lwl[tid] = lw[t * HH + tid]; }
    int wv = tid >> 6, lane = tid & 63;
    int dstn = blockIdx.y * 4 + wv;
    __syncthreads();
    if (dstn < Ndst) {
        float a = 0.f;
        int e0 = off[dstn], e1 = off[dstn + 1];
        for (int i = e0; i < e1; ++i) {
            int s = csr[i];
            float xs = x[(size_t)s * (TT * FF) + t * FF + lane];
            a += xs * rsqrtf(fmaxf(oc[s], 1.f));
        }
        a *= rsqrtf(fmaxf(ic[dstn], 1.f));
        accs[wv][lane] = a;
    }
    __syncthreads();
    if (dstn < Ndst) {
        float h0 = bl[lane], h1v = bl[64 + lane];
        #pragma unroll
        for (int f = 0; f < FF; ++f) {
            float af = accs[wv][f];
            h0  += af * wl[f * HH + lane];
            h1v += af * wl[f * HH + 64 + lane];
        }
        h0  = (h0  >= 0.f) ? h0  : 0.01f * h0;
        h1v = (h1v >= 0.f) ? h1v : 0.01f * h1v;
        float p = h0 * lwl[lane] + h1v * lwl[64 + lane];
        #pragma unroll
        for (int o2 = 32; o2 >= 1; o2 >>= 1) p += __shfl_down(p, o2);
        if (lane == 0) xseq[(size_t)(rowofs + dstn) * TT + t] = p + lb[t];
    }
}

// ---------------- input projection (layer 1): X = xin @ wih^T + (bih + bhh) ----------------
__global__ __launch_bounds__(256) void k_proj(
    const float* __restrict__ xin, int K,      // [N, K]
    const float* __restrict__ wih,             // [512, K]
    const float* __restrict__ bih, const float* __restrict__ bhh,
    float* __restrict__ Xout, int N)           // [N, 512]
{
    __shared__ float xt[16 * 128];
    int n0 = blockIdx.x * 16, tid = threadIdx.x;
    for (int i = tid; i < 16 * K; i += 256) {
        int nn = i / K, kk = i - nn * K;
        int n = n0 + nn;
        xt[i] = (n < N) ? xin[(size_t)n * K + kk] : 0.f;
    }
    __syncthreads();
    float acc0[16], acc1[16];
    #pragma unroll
    for (int i = 0; i < 16; ++i) { acc0[i] = 0.f; acc1[i] = 0.f; }
    int r0 = tid, r1 = tid + 256;
    for (int k = 0; k < K; ++k) {
        float w0 = wih[(size_t)r0 * K + k];
        float w1 = wih[(size_t)r1 * K + k];
        #pragma unroll
        for (int i = 0; i < 16; ++i) {
            float xv = xt[i * K + k];
            acc0[i] += xv * w0;
            acc1[i] += xv * w1;
        }
    }
    float b0 = bih[r0] + bhh[r0], b1 = bih[r1] + bhh[r1];
    for (int i = 0; i < 16; ++i) {
        int n = n0 + i;
        if (n < N) {
            Xout[(size_t)n * 512 + r0] = acc0[i] + b0;
            Xout[(size_t)n * 512 + r1] = acc1[i] + b1;
        }
    }
}

// ---------------- sequential LSTM recurrence (one block = one CU) ----------------
// thread = (j,p): unit j = tid>>2, k-chunk/gate p = tid&3.
// w[g][k] in VGPRs; h chunk read from padded LDS (stride 36 words, conflict-free);
// reduce-scatter (3 shfl) -> lane p holds gate p; one activation per lane;
// gather (3 shfl) -> lane 0 computes c,h; single fast barrier per step.
__device__ void lstm_rec(const float* __restrict__ X, const float* __restrict__ Whh,
                         float* __restrict__ Hout, bool agent_x, bool agent_h,
                         int* wflag, int* sflag)
{
    __shared__ __align__(16) float hb[2][4 * 36];
    const int tid = threadIdx.x;
    const int j = tid >> 2, p = tid & 3;
    float w[4][32];
    #pragma unroll
    for (int g = 0; g < 4; ++g) {
        const float4* wr = reinterpret_cast<const float4*>(Whh + (size_t)(g * HH + j) * HH + p * 32);
        #pragma unroll
        for (int k4 = 0; k4 < 8; ++k4) {
            float4 v = wr[k4];
            w[g][4*k4+0] = v.x; w[g][4*k4+1] = v.y;
            w[g][4*k4+2] = v.z; w[g][4*k4+3] = v.w;
        }
    }
    if (tid < HH) hb[0][(tid >> 5) * 36 + (tid & 31)] = 0.f;
    // activation constants: sigmoid (p=0,1,3): a = 1/(1+e^-s); tanh (p=2): a = 1 - 2/(1+e^2s)
    const float k1 = (p == 2) ? -2.f : 1.f;
    const float k2 = (p == 2) ? 2.f : -1.f;
    const float k3 = (p == 2) ? 1.f : 0.f;
    float c = 0.f;        // meaningful on p==0 lanes only
    int cur = 0;
    __syncthreads();
    for (int ch = 0; ch < NCH; ++ch) {
        const int n0 = ch * CHK;
        const int n1 = (n0 + CHK < NTOT) ? (n0 + CHK) : NTOT;
        if (wflag) {
            if (tid == 0) {
                while (__hip_atomic_load(wflag + ch, __ATOMIC_RELAXED, __HIP_MEMORY_SCOPE_AGENT) == 0)
                    __builtin_amdgcn_s_sleep(2);
            }
            __syncthreads();
            __threadfence();   // acquire: invalidate stale cache before reading chunk
        }
        const float* xp = X + (size_t)n0 * 512 + p * HH + j;
        float xcur = agent_x ? ld_agent(xp) : xp[0];
        float xn1 = (n0 + 1 < n1) ? (agent_x ? ld_agent(xp + 512) : xp[512]) : 0.f;
        for (int n = n0; n < n1; ++n) {
            float xn2 = 0.f;
            if (n + 2 < n1) {
                const float* q = xp + (size_t)(n + 2 - n0) * 512;
                xn2 = agent_x ? ld_agent(q) : q[0];
            }
            const float4* hr = reinterpret_cast<const float4*>(&hb[cur][p * 36]);
            float h[32];
            #pragma unroll
            for (int k4 = 0; k4 < 8; ++k4) {
                float4 v4 = hr[k4];
                h[4*k4+0] = v4.x; h[4*k4+1] = v4.y;
                h[4*k4+2] = v4.z; h[4*k4+3] = v4.w;
            }
            float s0 = 0.f, s1 = 0.f, s2 = 0.f, s3 = 0.f;
            #pragma unroll
            for (int k = 0; k < 32; ++k) {
                float hv = h[k];
                s0 = fmaf(w[0][k], hv, s0);
                s1 = fmaf(w[1][k], hv, s1);
                s2 = fmaf(w[2][k], hv, s2);
                s3 = fmaf(w[3][k], hv, s3);
            }
            // reduce-scatter over the 4 p-lanes: lane p ends with gate p total
            float zA = (p & 1) ? s0 : s1;
            float rA = __shfl_xor(zA, 1);
            float u  = ((p & 1) ? s1 : s0) + rA;      // gate (p&1), half-sum
            float zB = (p & 1) ? s2 : s3;
            float rB = __shfl_xor(zB, 1);
            float v  = ((p & 1) ? s3 : s2) + rB;      // gate 2+(p&1), half-sum
            float zC = (p & 2) ? u : v;
            float rC = __shfl_xor(zC, 2);
            float sf = (((p & 2) ? v : u) + rC) + xcur;
            // single activation per lane
            float e = __expf(k2 * sf);
            float a = fmaf(k1, __builtin_amdgcn_rcpf(1.f + e), k3);
            // gather i,f,g,o to lane p==0
            float af = __shfl_xor(a, 1);
            float ag = __shfl_xor(a, 2);
            float ao = __shfl_xor(a, 3);
            c = fmaf(af, c, a * ag);                  // valid on p==0
            float e2 = __expf(2.f * c);
            float th = fmaf(-2.f, __builtin_amdgcn_rcpf(1.f + e2), 1.f);
            float hnew = ao * th;
            if (p == 0) {
                hb[cur ^ 1][(j >> 5) * 36 + (j & 31)] = hnew;
                if (agent_h) st_agent(Hout + (size_t)n * HH + j, hnew);
                else         Hout[(size_t)n * HH + j] = hnew;
            }
            bar_fast();          // lgkmcnt only: global ops stay in flight
            cur ^= 1;
            xcur = xn1; xn1 = xn2;
        }
        if (sflag) {
            __syncthreads();     // full drain (vmcnt0): h stores visible, X reads consumed
            if (tid == 0)
                __hip_atomic_store(sflag + ch, 1, __ATOMIC_RELEASE, __HIP_MEMORY_SCOPE_AGENT);
        }
    }
}

// ---------------- layer-2 input projection worker (pipelined) ----------------
__device__ void proj_work(const float* __restrict__ h1, const float* __restrict__ Wih,
                          const float* __restrict__ bih, const float* __restrict__ bhh,
                          float* __restrict__ X2, int* wflag, int* sflag)
{
    __shared__ float hl[CHK * HH];     // 32 KB
    const int tid = threadIdx.x;       // row r of W_ih1 (gate-major)
    const float bsum = bih[tid] + bhh[tid];
    const float4* wr = reinterpret_cast<const float4*>(Wih + (size_t)tid * HH);
    for (int ch = 0; ch < NCH; ++ch) {
        const int n0 = ch * CHK;
        const int cnt = (n0 + CHK < NTOT) ? CHK : (NTOT - n0);
        if (tid == 0) {
            while (__hip_atomic_load(wflag + ch, __ATOMIC_RELAXED, __HIP_MEMORY_SCOPE_AGENT) == 0)
                __builtin_amdgcn_s_sleep(2);
        }
        __syncthreads();
        __threadfence();
        for (int i = tid; i < cnt * HH; i += 512)
            hl[i] = ld_agent(h1 + (size_t)n0 * HH + i);
        __syncthreads();
        for (int t0 = 0; t0 < cnt; t0 += 16) {
            float acc[16];
            #pragma unroll
            for (int i = 0; i < 16; ++i) acc[i] = bsum;
            for (int k4 = 0; k4 < HH / 4; ++k4) {
                float4 wv = wr[k4];
                #pragma unroll
                for (int i = 0; i < 16; ++i) {
                    const float* hh = &hl[(t0 + i) * HH + 4 * k4];
                    acc[i] += wv.x*hh[0] + wv.y*hh[1] + wv.z*hh[2] + wv.w*hh[3];
                }
            }
            int tl = cnt - t0; if (tl > 16) tl = 16;
            for (int i = 0; i < tl; ++i)
                st_agent(X2 + (size_t)(n0 + t0 + i) * 512 + tid, acc[i]);
        }
        __syncthreads();   // drain stores
        if (tid == 0)
            __hip_atomic_store(sflag + ch, 1, __ATOMIC_RELEASE, __HIP_MEMORY_SCOPE_AGENT);
    }
}

// ---------------- 3-stage pipeline: L1 rec -> proj -> L2 rec ----------------
__global__ __launch_bounds__(512) void k_pipe(
    const float* __restrict__ X1, const float* __restrict__ w_hh0, float* __restrict__ h1,
    const float* __restrict__ w_ih1, const float* __restrict__ b_ih1, const float* __restrict__ b_hh1,
    float* __restrict__ X2, const float* __restrict__ w_hh1, float* __restrict__ out,
    int* flags1, int* flags2)
{
    if (blockIdx.x == 0)
        lstm_rec(X1, w_hh0, h1, false, true, nullptr, flags1);
    else if (blockIdx.x == 1)
        proj_work(h1, w_ih1, b_ih1, b_hh1, X2, flags1, flags2);
    else
        lstm_rec(X2, w_hh1, out, true, false, flags2, nullptr);
}

extern "C" void kernel_launch(void* const* d_in, const int* in_sizes, int n_in,
                              void* d_out, int out_size, void* d_ws, size_t ws_size,
                              hipStream_t stream) {
    const float* feat_svc = (const float*)d_in[0];
    const float* feat_pod = (const float*)d_in[1];
    const float* feat_node= (const float*)d_in[2];
    const float* w_svc = (const float*)d_in[3];
    const float* b_svc = (const float*)d_in[4];
    const float* w_in  = (const float*)d_in[5];
    const float* b_in  = (const float*)d_in[6];
    const float* w_ni  = (const float*)d_in[7];
    const float* b_ni  = (const float*)d_in[8];
    const float* lw_svc = (const float*)d_in[9];
    const float* lb_svc = (const float*)d_in[10];
    const float* lw_pod = (const float*)d_in[11];
    const float* lb_pod = (const float*)d_in[12];
    const float* lw_node= (const float*)d_in[13];
    const float* lb_node= (const float*)d_in[14];
    const float* w_ih0 = (const float*)d_in[15];
    const float* w_hh0 = (const float*)d_in[16];
    const float* b_ih0 = (const float*)d_in[17];
    const float* b_hh0 = (const float*)d_in[18];
    const float* w_ih1 = (const float*)d_in[19];
    const float* w_hh1 = (const float*)d_in[20];
    const float* b_ih1 = (const float*)d_in[21];
    const float* b_hh1 = (const float*)d_in[22];
    const int* eA_src = (const int*)d_in[23];   // svc -> svc
    const int* eA_dst = (const int*)d_in[24];
    const int* eB_src = (const int*)d_in[25];   // pod -> node
    const int* eB_dst = (const int*)d_in[26];
    const int* eC_src = (const int*)d_in[27];   // node -> pod
    const int* eC_dst = (const int*)d_in[28];

    float* ws = (float*)d_ws;
    // layout (4B units)
    float* ocA = ws + 0;        // 2000
    float* icA = ws + 2000;     // 2000
    float* ocB = ws + 4000;     // 8000 (pod out-deg)
    float* icB = ws + 12000;    // 1000 (node in-deg)
    float* ocC = ws + 13000;    // 1000 (node out-deg)
    float* icC = ws + 14000;    // 8000 (pod in-deg)
    int* curA = (int*)(ws + 22000);  // 2000
    int* curB = (int*)(ws + 24000);  // 1000
    int* curC = (int*)(ws + 25000);  // 8000
    int* offA = (int*)(ws + 33000);  // 2001
    int* offB = (int*)(ws + 35001);  // 1001
    int* offC = (int*)(ws + 36002);  // 8001
    int* sA   = (int*)(ws + 44003);  // 30000
    int* sB   = (int*)(ws + 74003);  // 24000
    int* sC   = (int*)(ws + 98003);  // 24000
    float* xseq = ws + 122003;       // 11000*32
    float* X1   = ws + 474003;       // 11000*512
    float* h1   = ws + 6106003;      // 11000*128
    int* flags1 = (int*)(ws + 7514003);   // NCH
    int* flags2 = flags1 + NCH;           // NCH
    float* X2   = X1;   // layer-2 proj overwrites X1 chunk-in-place (safe: gated by flags1)

    // zero deg counts + cursors + pipeline flags
    hipMemsetAsync(d_ws, 0, 33000 * sizeof(float), stream);
    hipMemsetAsync(flags1, 0, 2 * NCH * sizeof(int), stream);

    k_count<<<(EA + 255) / 256, 256, 0, stream>>>(eA_src, eA_dst, EA, ocA, icA);
    k_count<<<(EB + 255) / 256, 256, 0, stream>>>(eB_src, eB_dst, EB, ocB, icB);
    k_count<<<(EC + 255) / 256, 256, 0, stream>>>(eC_src, eC_dst, EC, ocC, icC);

    k_scan<<<3, 256, 0, stream>>>(icA, NSVC, offA, icB, NNODE, offB, icC, NPOD, offC);

    k_scatter<<<(EA + 255) / 256, 256, 0, stream>>>(eA_src, eA_dst, EA, offA, curA, sA);
    k_scatter<<<(EB + 255) / 256, 256, 0, stream>>>(eB_src, eB_dst, EB, offB, curB, sB);
    k_scatter<<<(EC + 255) / 256, 256, 0, stream>>>(eC_src, eC_dst, EC, offC, curC, sC);

    // conv A: svc->svc, rows [0, 2000)
    k_conv<<<dim3(TT, (NSVC + 3) / 4), 256, 0, stream>>>(
        feat_svc, w_svc, b_svc, lw_svc, lb_svc, ocA, icA, offA, sA, xseq, NSVC, 0);
    // conv C: node->pod (h_pod), rows [2000, 10000)
    k_conv<<<dim3(TT, (NPOD + 3) / 4), 256, 0, stream>>>(
        feat_node, w_ni, b_ni, lw_pod, lb_pod, ocC, icC, offC, sC, xseq, NPOD, NSVC);
    // conv B: pod->node (h_node), rows [10000, 11000)
    k_conv<<<dim3(TT, (NNODE + 3) / 4), 256, 0, stream>>>(
        feat_pod, w_in, b_in, lw_node, lb_node, ocB, icB, offB, sB, xseq, NNODE, NSVC + NPOD);

    // layer-1 input projection (parallel GEMM)
    k_proj<<<(NTOT + 15) / 16, 256, 0, stream>>>(xseq, TT, w_ih0, b_ih0, b_hh0, X1, NTOT);

    // 3-stage pipelined LSTM: L1 recurrence -> L2 proj -> L2 recurrence
    k_pipe<<<3, 512, 0, stream>>>(X1, w_hh0, h1, w_ih1, b_ih1, b_hh1,
                                  X2, w_hh1, (float*)d_out, flags1, flags2);
}